// Round 2
// baseline (403.992 us; speedup 1.0000x reference)
//
#include <hip/hip_runtime.h>

// GIN 2-layer via linearity:
//   z1 = (I+A)x ; hid = z1@W1^T + b1
//   z2 = (I+A)z1 ; out = z2@(W2W1)^T + (1+deg)*(W2b1) + b2
// bf16 gathers (fp8 fails accuracy: absmax 4.94 > 2.5). CSR via fixed-
// capacity radix buckets. Round 2: fused agg+gemm per layer (z2 never hits
// HBM; z1 gemm-read served from LDS), cast fused into scatter (xb lives in
// dead `out` region), prep fused into build_csr, bcur init via memset.
// 5 dispatches + 1 memset (was 9 dispatches).

#define DFEAT 128
#define BSHIFT 8
#define NB_MAX 512
#define CAP 8192   // per-bucket capacity; mean 4096, 64-sigma safe

typedef __attribute__((ext_vector_type(8))) short short8;
typedef __attribute__((ext_vector_type(4))) float f32x4;

__device__ __forceinline__ float bf2f(unsigned short u) {
    union { unsigned int i; float f; } c;
    c.i = ((unsigned int)u) << 16;
    return c.f;
}
__device__ __forceinline__ unsigned short f2b(float f) {
    union { float f; unsigned int i; } c;
    c.f = f;
    unsigned int u = c.i;
    u = (u + 0x7FFFu + ((u >> 16) & 1u)) >> 16;   // RNE
    return (unsigned short)u;
}

// ---------------- fused bucket_scatter + cast_bf16 ----------------
// blocks [0,nscat): radix-bucket edge scatter. blocks [nscat,..): x -> bf16.
// bcur is a per-bucket COUNT (memset 0); absolute base = b*CAP + count.

__global__ __launch_bounds__(256) void scatter_cast(const int* __restrict__ src,
                                                    const int* __restrict__ dst,
                                                    int* __restrict__ bcur,
                                                    int* __restrict__ ebuf, int E,
                                                    int nscat,
                                                    const float* __restrict__ x,
                                                    unsigned short* __restrict__ xb,
                                                    int total4) {
    int tid = threadIdx.x;
    if (blockIdx.x >= nscat) {
        int i = (blockIdx.x - nscat) * 256 + tid;
        if (i < total4) {
            float4 v = ((const float4*)x)[i];
            ushort4 o;
            o.x = f2b(v.x); o.y = f2b(v.y); o.z = f2b(v.z); o.w = f2b(v.w);
            ((ushort4*)xb)[i] = o;
        }
        return;
    }
    __shared__ int lh[NB_MAX];
    for (int i = tid; i < NB_MAX; i += 256) lh[i] = 0;
    __syncthreads();
    int e0 = blockIdx.x * 4096;
    int e1 = min(e0 + 4096, E);
    int s[16], d[16];
    #pragma unroll
    for (int j = 0; j < 16; j++) {
        int e = e0 + tid + 256 * j;
        if (e < e1) { s[j] = src[e]; d[j] = dst[e]; atomicAdd(&lh[d[j] >> BSHIFT], 1); }
    }
    __syncthreads();
    for (int i = tid; i < NB_MAX; i += 256) {
        int c = lh[i];
        lh[i] = c ? (i * CAP + atomicAdd(&bcur[i], c)) : 0;  // absolute base
    }
    __syncthreads();
    #pragma unroll
    for (int j = 0; j < 16; j++) {
        int e = e0 + tid + 256 * j;
        if (e < e1) {
            int b = d[j] >> BSHIFT;
            int p = atomicAdd(&lh[b], 1);
            if (p < (b + 1) * CAP) ebuf[p] = (s[j] << 8) | (d[j] & 255);
        }
    }
}

// ---------------- fused build_csr + prep_w ----------------
// blocks [0,nbk): per-bucket hist+scan+scatter -> rpse, esrc.
// blocks [nbk, nbk+64): weight prep, 2 rows per block.

__global__ __launch_bounds__(256) void csr_prep(const int* __restrict__ ebuf,
                                                const int* __restrict__ bcur,
                                                int2* __restrict__ rpse,
                                                int* __restrict__ esrc, int n, int nbk,
                                                const float* __restrict__ W1,
                                                const float* __restrict__ W2,
                                                const float* __restrict__ b1,
                                                unsigned short* __restrict__ Wb1,
                                                unsigned short* __restrict__ Wcb,
                                                float* __restrict__ w2b1) {
    int tid = threadIdx.x;
    if (blockIdx.x >= nbk) {
        // weight prep: rows i = (bb*2) and (bb*2+1)
        __shared__ float red[256];
        int bb = blockIdx.x - nbk;
        int i = bb * 2 + (tid >> 7);
        int j = tid & 127;
        float s = 0.f;
        #pragma unroll 4
        for (int k = 0; k < 128; k++) s += W2[i * 128 + k] * W1[k * 128 + j];
        Wcb[i * 128 + j] = f2b(s);
        Wb1[i * 128 + j] = f2b(W1[i * 128 + j]);
        red[tid] = W2[i * 128 + j] * b1[j];
        __syncthreads();
        if (j == 0) {
            float t = 0.f;
            for (int k = 0; k < 128; k++) t += red[tid + k];
            w2b1[i] = t;
        }
        return;
    }
    __shared__ int hist[256];
    __shared__ int wsum[4];
    __shared__ int woff2[4];
    int b = blockIdx.x;
    int nbase = b << BSHIFT;
    int e0 = b * CAP;
    int e1 = e0 + min(bcur[b], CAP);
    hist[tid] = 0;
    __syncthreads();
    for (int e = e0 + tid; e < e1; e += 256)
        atomicAdd(&hist[ebuf[e] & 255], 1);
    __syncthreads();
    int v = hist[tid];
    int lane = tid & 63, wid = tid >> 6;
    int inc = v;
    #pragma unroll
    for (int off = 1; off < 64; off <<= 1) {
        int u = __shfl_up(inc, off, 64);
        if (lane >= off) inc += u;
    }
    if (lane == 63) wsum[wid] = inc;
    __syncthreads();
    if (tid == 0) {
        int run = 0;
        #pragma unroll
        for (int w = 0; w < 4; w++) { woff2[w] = run; run += wsum[w]; }
    }
    __syncthreads();
    int excl = woff2[wid] + inc - v;
    int node = nbase + tid;
    if (node < n) rpse[node] = make_int2(e0 + excl, e0 + excl + v);
    __syncthreads();
    hist[tid] = excl;
    __syncthreads();
    for (int e = e0 + tid; e < e1; e += 256) {
        int le = ebuf[e];
        int p = atomicAdd(&hist[le & 255], 1);
        esrc[e0 + p] = ((unsigned int)le) >> 8;
    }
}

// ---------------- fused aggregation + GEMM ----------------
// Block = 256 threads = 64 nodes. Phase A: each wave aggregates its 16 rows
// (2 nodes at a time, half-wave per node, 8 gathers in flight, 32-bit saddr
// offsets) into an LDS tile with 272 B row stride (conflict-free b128 reads).
// Phase B: MFMA from LDS.

__device__ __forceinline__ ushort4 agg_node(const char* zb,
                                            const int2* __restrict__ rpse,
                                            const int* __restrict__ esrc,
                                            int node, int n, int hl, int sbase,
                                            unsigned lb) {
    float a0 = 0.f, a1 = 0.f, a2 = 0.f, a3 = 0.f;
    if (node < n) {
        int2 se = rpse[node];
        int e0 = se.x, deg = se.y - se.x;
        ushort4 sv = *(const ushort4*)(zb + ((unsigned)node * 256u + lb));
        a0 = bf2f(sv.x); a1 = bf2f(sv.y); a2 = bf2f(sv.z); a3 = bf2f(sv.w);
        int eidx = (hl < deg) ? esrc[e0 + hl] : 0;
        int m = min(deg, 32);
        int j = 0;
        for (; j + 8 <= m; j += 8) {
            unsigned off[8];
            ushort4 vv[8];
            #pragma unroll
            for (int k = 0; k < 8; k++)
                off[k] = (unsigned)__shfl(eidx, sbase + j + k) * 256u + lb;
            #pragma unroll
            for (int k = 0; k < 8; k++) vv[k] = *(const ushort4*)(zb + off[k]);
            #pragma unroll
            for (int k = 0; k < 8; k++) {
                a0 += bf2f(vv[k].x); a1 += bf2f(vv[k].y);
                a2 += bf2f(vv[k].z); a3 += bf2f(vv[k].w);
            }
        }
        for (; j < m; j++) {
            unsigned off = (unsigned)__shfl(eidx, sbase + j) * 256u + lb;
            ushort4 v = *(const ushort4*)(zb + off);
            a0 += bf2f(v.x); a1 += bf2f(v.y); a2 += bf2f(v.z); a3 += bf2f(v.w);
        }
        for (int e = e0 + 32; e < e0 + deg; e++) {   // rare deg>32 tail
            unsigned off = (unsigned)esrc[e] * 256u + lb;
            ushort4 v = *(const ushort4*)(zb + off);
            a0 += bf2f(v.x); a1 += bf2f(v.y); a2 += bf2f(v.z); a3 += bf2f(v.w);
        }
    }
    ushort4 o;
    o.x = f2b(a0); o.y = f2b(a1); o.z = f2b(a2); o.w = f2b(a3);
    return o;
}

#define LROWS 136   // LDS row stride in shorts (272 B): conflict-free b128

// layer 1: writes z1 (bf16, global) + hid = z1@W1^T + b1
__global__ __launch_bounds__(256) void fused_agg_gemm1(
        const ushort4* __restrict__ zin4, const int2* __restrict__ rpse,
        const int* __restrict__ esrc, const unsigned short* __restrict__ Wb,
        const float* __restrict__ bias, ushort4* __restrict__ zout4,
        float* __restrict__ out, int n) {
    __shared__ __align__(16) short lt[64 * LROWS];
    int nbase = blockIdx.x * 64;
    int w = threadIdx.x >> 6;
    int hl = threadIdx.x & 31;
    int sbase = threadIdx.x & 32;
    int half = (threadIdx.x >> 5) & 1;
    unsigned lb = (unsigned)hl * 8u;
    const char* zb = (const char*)zin4;
    for (int it = 0; it < 8; ++it) {
        int lrow = w * 16 + it * 2 + half;
        int node = nbase + lrow;
        ushort4 o = agg_node(zb, rpse, esrc, node, n, hl, sbase, lb);
        *(ushort4*)((char*)lt + lrow * (LROWS * 2) + lb) = o;
        if (node < n) zout4[(size_t)node * 32 + hl] = o;
    }
    __syncthreads();
    int lane = threadIdx.x & 63;
    int m = lane & 15, q = lane >> 4;
    const short* ap = lt + (w * 16 + m) * LROWS + q * 8;
    short8 a0 = *(const short8*)(ap);
    short8 a1 = *(const short8*)(ap + 32);
    short8 a2 = *(const short8*)(ap + 64);
    short8 a3 = *(const short8*)(ap + 96);
    f32x4 acc[8];
    #pragma unroll
    for (int c = 0; c < 8; c++) acc[c] = (f32x4){0.f, 0.f, 0.f, 0.f};
    #pragma unroll
    for (int c = 0; c < 8; c++) {
        const short* wp = (const short*)Wb + (c * 16 + m) * 128 + q * 8;
        short8 b0 = *(const short8*)(wp);
        short8 b1v = *(const short8*)(wp + 32);
        short8 b2v = *(const short8*)(wp + 64);
        short8 b3v = *(const short8*)(wp + 96);
        acc[c] = __builtin_amdgcn_mfma_f32_16x16x32_bf16(a0, b0, acc[c], 0, 0, 0);
        acc[c] = __builtin_amdgcn_mfma_f32_16x16x32_bf16(a1, b1v, acc[c], 0, 0, 0);
        acc[c] = __builtin_amdgcn_mfma_f32_16x16x32_bf16(a2, b2v, acc[c], 0, 0, 0);
        acc[c] = __builtin_amdgcn_mfma_f32_16x16x32_bf16(a3, b3v, acc[c], 0, 0, 0);
    }
    int row0 = nbase + w * 16 + q * 4;
    #pragma unroll
    for (int c = 0; c < 8; c++) {
        float bb = bias[c * 16 + m];
        #pragma unroll
        for (int r = 0; r < 4; r++) {
            int node = row0 + r;
            if (node < n) out[(size_t)node * 128 + c * 16 + m] = acc[c][r] + bb;
        }
    }
}

// layer 2: z2 never materialized; out = z2@Wc^T + (1+deg)*w2b1 + b2
__global__ __launch_bounds__(256) void fused_agg_gemm2(
        const ushort4* __restrict__ zin4, const int2* __restrict__ rpse,
        const int* __restrict__ esrc, const unsigned short* __restrict__ Wb,
        const float* __restrict__ w2b1, const float* __restrict__ bias2,
        float* __restrict__ out, int n) {
    __shared__ __align__(16) short lt[64 * LROWS];
    int nbase = blockIdx.x * 64;
    int w = threadIdx.x >> 6;
    int hl = threadIdx.x & 31;
    int sbase = threadIdx.x & 32;
    int half = (threadIdx.x >> 5) & 1;
    unsigned lb = (unsigned)hl * 8u;
    const char* zb = (const char*)zin4;
    for (int it = 0; it < 8; ++it) {
        int lrow = w * 16 + it * 2 + half;
        int node = nbase + lrow;
        ushort4 o = agg_node(zb, rpse, esrc, node, n, hl, sbase, lb);
        *(ushort4*)((char*)lt + lrow * (LROWS * 2) + lb) = o;
    }
    __syncthreads();
    int lane = threadIdx.x & 63;
    int m = lane & 15, q = lane >> 4;
    const short* ap = lt + (w * 16 + m) * LROWS + q * 8;
    short8 a0 = *(const short8*)(ap);
    short8 a1 = *(const short8*)(ap + 32);
    short8 a2 = *(const short8*)(ap + 64);
    short8 a3 = *(const short8*)(ap + 96);
    f32x4 acc[8];
    #pragma unroll
    for (int c = 0; c < 8; c++) acc[c] = (f32x4){0.f, 0.f, 0.f, 0.f};
    #pragma unroll
    for (int c = 0; c < 8; c++) {
        const short* wp = (const short*)Wb + (c * 16 + m) * 128 + q * 8;
        short8 b0 = *(const short8*)(wp);
        short8 b1v = *(const short8*)(wp + 32);
        short8 b2v = *(const short8*)(wp + 64);
        short8 b3v = *(const short8*)(wp + 96);
        acc[c] = __builtin_amdgcn_mfma_f32_16x16x32_bf16(a0, b0, acc[c], 0, 0, 0);
        acc[c] = __builtin_amdgcn_mfma_f32_16x16x32_bf16(a1, b1v, acc[c], 0, 0, 0);
        acc[c] = __builtin_amdgcn_mfma_f32_16x16x32_bf16(a2, b2v, acc[c], 0, 0, 0);
        acc[c] = __builtin_amdgcn_mfma_f32_16x16x32_bf16(a3, b3v, acc[c], 0, 0, 0);
    }
    int row0 = nbase + w * 16 + q * 4;
    float degf[4];
    #pragma unroll
    for (int r = 0; r < 4; r++) {
        int node = row0 + r;
        if (node < n) {
            int2 se = rpse[node];
            degf[r] = (float)(1 + se.y - se.x);
        } else degf[r] = 0.f;
    }
    #pragma unroll
    for (int c = 0; c < 8; c++) {
        int col = c * 16 + m;
        float wb = w2b1[col];
        float bb = bias2[col];
        #pragma unroll
        for (int r = 0; r < 4; r++) {
            int node = row0 + r;
            if (node < n) out[(size_t)node * 128 + col] = acc[c][r] + degf[r] * wb + bb;
        }
    }
}

// ---------------- launch ----------------

extern "C" void kernel_launch(void* const* d_in, const int* in_sizes, int n_in,
                              void* d_out, int out_size, void* d_ws, size_t ws_size,
                              hipStream_t stream) {
    const float* x  = (const float*)d_in[0];
    const int*   ei = (const int*)d_in[1];
    const float* W1 = (const float*)d_in[2];
    const float* b1 = (const float*)d_in[3];
    const float* W2 = (const float*)d_in[4];
    const float* b2 = (const float*)d_in[5];

    const int n = in_sizes[0] / DFEAT;   // 100000
    const int E = in_sizes[1] / 2;       // 1600000
    const int* src = ei;
    const int* dst = ei + E;
    const int nbuckets = (n + (1 << BSHIFT) - 1) >> BSHIFT;   // 391

    float* out = (float*)d_out;
    float* hid = out + (size_t)n * DFEAT;

    // xb lives in the dead `out` region (fp32 out = 51.2 MB >= 25.6 MB bf16;
    // out is only written by fused_agg_gemm2, after xb is dead).
    unsigned short* xb = (unsigned short*)out;

    // workspace: z1b | ebuf | esrc | rpse | bcur | weights
    char* w = (char*)d_ws;
    const size_t szB = (size_t)n * DFEAT * sizeof(unsigned short);   // 25.6 MB
    unsigned short* z1b = (unsigned short*)w;
    int* ebuf = (int*)(w + szB);                 // nbuckets*CAP ints = 12.8 MB
    int* esrc = (int*)(w + 2 * szB);             // nbuckets*CAP = 12.8 MB
    int2* rpse = (int2*)(esrc + (size_t)nbuckets * CAP);
    int* bcur = (int*)(rpse + n);
    char* wp = (char*)(bcur + NB_MAX);
    unsigned short* Wb1 = (unsigned short*)wp;
    unsigned short* Wcb = Wb1 + DFEAT * DFEAT;
    float* w2b1 = (float*)(Wcb + DFEAT * DFEAT);

    const int cast_blocks = (n * 32 + 255) / 256;   // 12500
    hipMemsetAsync(bcur, 0, nbuckets * sizeof(int), stream);
    scatter_cast<<<nbuckets + cast_blocks, 256, 0, stream>>>(
        src, dst, bcur, ebuf, E, nbuckets, x, xb, n * 32);
    csr_prep<<<nbuckets + 64, 256, 0, stream>>>(
        ebuf, bcur, rpse, esrc, n, nbuckets, W1, W2, b1, Wb1, Wcb, w2b1);

    const int gemm_blocks = (n + 63) / 64;   // 1563
    fused_agg_gemm1<<<gemm_blocks, 256, 0, stream>>>(
        (const ushort4*)xb, rpse, esrc, Wb1, b1, (ushort4*)z1b, hid, n);
    fused_agg_gemm2<<<gemm_blocks, 256, 0, stream>>>(
        (const ushort4*)z1b, rpse, esrc, Wcb, w2b1, b2, out, n);
}

// Round 4
// 372.246 us; speedup vs baseline: 1.0853x; 1.0853x over previous
//
#include <hip/hip_runtime.h>

// GIN 2-layer via linearity:
//   z1 = (I+A)x ; hid = z1@W1^T + b1
//   z2 = (I+A)z1 ; out = z2@(W2W1)^T + (1+deg)*(W2b1) + b2
// Round 3 (resubmit; R3 bench was an infra failure): agg is latency-bound
// (R2 counters: occ 36%, hbm 28%, valu 18%).
// -> 16 nodes/block (grid 6250, 4x block concurrency), 16B gathers (short8,
//    16-lane group per row, 2x bytes-in-flight/wave), zero-row padding at
//    index n (branch-free 8-deep gather rounds, no serialized tail).

#define DFEAT 128
#define BSHIFT 8
#define NB_MAX 512
#define CAP 8192   // per-bucket capacity; mean 4096, 64-sigma safe
#define LROWS 136  // LDS row stride in shorts (272 B)

typedef __attribute__((ext_vector_type(8))) short short8;
typedef __attribute__((ext_vector_type(4))) float f32x4;

__device__ __forceinline__ float bf2f(unsigned short u) {
    union { unsigned int i; float f; } c;
    c.i = ((unsigned int)u) << 16;
    return c.f;
}
__device__ __forceinline__ unsigned short f2b(float f) {
    union { float f; unsigned int i; } c;
    c.f = f;
    unsigned int u = c.i;
    u = (u + 0x7FFFu + ((u >> 16) & 1u)) >> 16;   // RNE
    return (unsigned short)u;
}

// ---------------- fused bucket_scatter + cast_bf16 ----------------
// blocks [0,nscat): radix-bucket edge scatter. blocks [nscat,..): x -> bf16.
// bcur is a per-bucket COUNT (memset 0); absolute base = b*CAP + count.
// First cast block also zeroes xb row n (gather zero-row).

__global__ __launch_bounds__(256) void scatter_cast(const int* __restrict__ src,
                                                    const int* __restrict__ dst,
                                                    int* __restrict__ bcur,
                                                    int* __restrict__ ebuf, int E,
                                                    int nscat,
                                                    const float* __restrict__ x,
                                                    unsigned short* __restrict__ xb,
                                                    int total4, int nzero) {
    int tid = threadIdx.x;
    if (blockIdx.x >= nscat) {
        int i = (blockIdx.x - nscat) * 256 + tid;
        if (i < total4) {
            float4 v = ((const float4*)x)[i];
            ushort4 o;
            o.x = f2b(v.x); o.y = f2b(v.y); o.z = f2b(v.z); o.w = f2b(v.w);
            ((ushort4*)xb)[i] = o;
        }
        if (blockIdx.x == nscat && tid < 32)   // zero-row at index nzero
            ((ushort4*)xb)[(size_t)nzero * 32 + tid] = make_ushort4(0, 0, 0, 0);
        return;
    }
    __shared__ int lh[NB_MAX];
    for (int i = tid; i < NB_MAX; i += 256) lh[i] = 0;
    __syncthreads();
    int e0 = blockIdx.x * 4096;
    int e1 = min(e0 + 4096, E);
    int s[16], d[16];
    #pragma unroll
    for (int j = 0; j < 16; j++) {
        int e = e0 + tid + 256 * j;
        if (e < e1) { s[j] = src[e]; d[j] = dst[e]; atomicAdd(&lh[d[j] >> BSHIFT], 1); }
    }
    __syncthreads();
    for (int i = tid; i < NB_MAX; i += 256) {
        int c = lh[i];
        lh[i] = c ? (i * CAP + atomicAdd(&bcur[i], c)) : 0;  // absolute base
    }
    __syncthreads();
    #pragma unroll
    for (int j = 0; j < 16; j++) {
        int e = e0 + tid + 256 * j;
        if (e < e1) {
            int b = d[j] >> BSHIFT;
            int p = atomicAdd(&lh[b], 1);
            if (p < (b + 1) * CAP) ebuf[p] = (s[j] << 8) | (d[j] & 255);
        }
    }
}

// ---------------- fused build_csr + prep_w ----------------

__global__ __launch_bounds__(256) void csr_prep(const int* __restrict__ ebuf,
                                                const int* __restrict__ bcur,
                                                int2* __restrict__ rpse,
                                                int* __restrict__ esrc, int n, int nbk,
                                                const float* __restrict__ W1,
                                                const float* __restrict__ W2,
                                                const float* __restrict__ b1,
                                                unsigned short* __restrict__ Wb1,
                                                unsigned short* __restrict__ Wcb,
                                                float* __restrict__ w2b1) {
    int tid = threadIdx.x;
    if (blockIdx.x >= nbk) {
        // weight prep: rows i = (bb*2) and (bb*2+1)
        __shared__ float red[256];
        int bb = blockIdx.x - nbk;
        int i = bb * 2 + (tid >> 7);
        int j = tid & 127;
        float s = 0.f;
        #pragma unroll 4
        for (int k = 0; k < 128; k++) s += W2[i * 128 + k] * W1[k * 128 + j];
        Wcb[i * 128 + j] = f2b(s);
        Wb1[i * 128 + j] = f2b(W1[i * 128 + j]);
        red[tid] = W2[i * 128 + j] * b1[j];
        __syncthreads();
        if (j == 0) {
            float t = 0.f;
            for (int k = 0; k < 128; k++) t += red[tid + k];
            w2b1[i] = t;
        }
        return;
    }
    __shared__ int hist[256];
    __shared__ int wsum[4];
    __shared__ int woff2[4];
    int b = blockIdx.x;
    int nbase = b << BSHIFT;
    int e0 = b * CAP;
    int e1 = e0 + min(bcur[b], CAP);
    hist[tid] = 0;
    __syncthreads();
    for (int e = e0 + tid; e < e1; e += 256)
        atomicAdd(&hist[ebuf[e] & 255], 1);
    __syncthreads();
    int v = hist[tid];
    int lane = tid & 63, wid = tid >> 6;
    int inc = v;
    #pragma unroll
    for (int off = 1; off < 64; off <<= 1) {
        int u = __shfl_up(inc, off, 64);
        if (lane >= off) inc += u;
    }
    if (lane == 63) wsum[wid] = inc;
    __syncthreads();
    if (tid == 0) {
        int run = 0;
        #pragma unroll
        for (int w = 0; w < 4; w++) { woff2[w] = run; run += wsum[w]; }
    }
    __syncthreads();
    int excl = woff2[wid] + inc - v;
    int node = nbase + tid;
    if (node < n) rpse[node] = make_int2(e0 + excl, e0 + excl + v);
    __syncthreads();
    hist[tid] = excl;
    __syncthreads();
    for (int e = e0 + tid; e < e1; e += 256) {
        int le = ebuf[e];
        int p = atomicAdd(&hist[le & 255], 1);
        esrc[e0 + p] = ((unsigned int)le) >> 8;
    }
}

// ---------------- fused aggregation + GEMM (16 nodes/block) ----------------
// Phase A: one node per 16-lane group (4 nodes/wave). 16B/lane gathers, 8 in
// flight, zero-row (index n) pads the last round -> branch-free inner loop.
// Phase B: 16-row MFMA tile from LDS; wave w computes col-blocks {2w, 2w+1}.

__device__ __forceinline__ void agg_node16(const char* __restrict__ zb,
                                           const int2* __restrict__ rpse,
                                           const int* __restrict__ esrc,
                                           int node, int nzero, int gl, int gbase,
                                           unsigned lb, float a[8]) {
    int2 se = rpse[node];
    int e0 = se.x, deg = se.y - se.x;
    short8 sv = *(const short8*)(zb + (unsigned)node * 256u + lb);
    #pragma unroll
    for (int t = 0; t < 8; t++) a[t] = bf2f((unsigned short)sv[t]);
    int rounds = (deg + 15) >> 4;
    for (int r = 0; r < rounds; ++r) {
        int ep = r * 16 + gl;
        int eidx = (ep < deg) ? esrc[e0 + ep] : nzero;
        unsigned off[8];
        short8 vv[8];
        #pragma unroll
        for (int k = 0; k < 8; k++)
            off[k] = (unsigned)__shfl(eidx, gbase + k) * 256u + lb;
        #pragma unroll
        for (int k = 0; k < 8; k++) vv[k] = *(const short8*)(zb + off[k]);
        #pragma unroll
        for (int k = 0; k < 8; k++) {
            #pragma unroll
            for (int t = 0; t < 8; t++) a[t] += bf2f((unsigned short)vv[k][t]);
        }
        #pragma unroll
        for (int k = 0; k < 8; k++)
            off[k] = (unsigned)__shfl(eidx, gbase + 8 + k) * 256u + lb;
        #pragma unroll
        for (int k = 0; k < 8; k++) vv[k] = *(const short8*)(zb + off[k]);
        #pragma unroll
        for (int k = 0; k < 8; k++) {
            #pragma unroll
            for (int t = 0; t < 8; t++) a[t] += bf2f((unsigned short)vv[k][t]);
        }
    }
}

// layer 1: writes z1 (bf16, global, + zero row) + hid = z1@W1^T + b1
__global__ __launch_bounds__(256) void fused_agg_gemm1(
        const ushort4* __restrict__ zin4, const int2* __restrict__ rpse,
        const int* __restrict__ esrc, const unsigned short* __restrict__ Wb,
        const float* __restrict__ bias, unsigned short* __restrict__ zout,
        float* __restrict__ out, int n) {
    __shared__ __align__(16) short lt[16 * LROWS];
    int nbase = blockIdx.x * 16;
    int w = threadIdx.x >> 6;
    int wl = threadIdx.x & 63;
    int gl = wl & 15, q = wl >> 4;
    int gbase = wl & 48;
    unsigned lb = (unsigned)gl * 16u;
    int lrow = w * 4 + q;
    int node = nbase + lrow;
    const char* zb = (const char*)zin4;

    float a[8];
    #pragma unroll
    for (int t = 0; t < 8; t++) a[t] = 0.f;
    if (node < n) agg_node16(zb, rpse, esrc, node, n, gl, gbase, lb, a);
    short8 o;
    #pragma unroll
    for (int t = 0; t < 8; t++) o[t] = (short)f2b(a[t]);
    *(short8*)((char*)lt + lrow * (LROWS * 2) + lb) = o;
    if (node < n) *(short8*)((char*)zout + (unsigned)node * 256u + lb) = o;
    if (blockIdx.x == 0 && threadIdx.x < 16) {   // zero-row for layer-2 gathers
        short8 z8;
        #pragma unroll
        for (int t = 0; t < 8; t++) z8[t] = 0;
        *(short8*)((char*)zout + (unsigned)n * 256u + threadIdx.x * 16) = z8;
    }
    __syncthreads();

    int m = gl;
    const short* ap = lt + m * LROWS + q * 8;
    short8 a0 = *(const short8*)(ap);
    short8 a1 = *(const short8*)(ap + 32);
    short8 a2 = *(const short8*)(ap + 64);
    short8 a3 = *(const short8*)(ap + 96);
    f32x4 acc[2];
    #pragma unroll
    for (int cc = 0; cc < 2; cc++) acc[cc] = (f32x4){0.f, 0.f, 0.f, 0.f};
    #pragma unroll
    for (int cc = 0; cc < 2; cc++) {
        int c = w * 2 + cc;
        const short* wp = (const short*)Wb + (c * 16 + m) * 128 + q * 8;
        short8 b0 = *(const short8*)(wp);
        short8 b1v = *(const short8*)(wp + 32);
        short8 b2v = *(const short8*)(wp + 64);
        short8 b3v = *(const short8*)(wp + 96);
        acc[cc] = __builtin_amdgcn_mfma_f32_16x16x32_bf16(a0, b0, acc[cc], 0, 0, 0);
        acc[cc] = __builtin_amdgcn_mfma_f32_16x16x32_bf16(a1, b1v, acc[cc], 0, 0, 0);
        acc[cc] = __builtin_amdgcn_mfma_f32_16x16x32_bf16(a2, b2v, acc[cc], 0, 0, 0);
        acc[cc] = __builtin_amdgcn_mfma_f32_16x16x32_bf16(a3, b3v, acc[cc], 0, 0, 0);
    }
    int row0 = nbase + q * 4;
    #pragma unroll
    for (int cc = 0; cc < 2; cc++) {
        int col = (w * 2 + cc) * 16 + m;
        float bb = bias[col];
        #pragma unroll
        for (int r = 0; r < 4; r++) {
            int nd = row0 + r;
            if (nd < n) out[(size_t)nd * 128 + col] = acc[cc][r] + bb;
        }
    }
}

// layer 2: z2 never materialized; out = z2@Wc^T + (1+deg)*w2b1 + b2
__global__ __launch_bounds__(256) void fused_agg_gemm2(
        const ushort4* __restrict__ zin4, const int2* __restrict__ rpse,
        const int* __restrict__ esrc, const unsigned short* __restrict__ Wb,
        const float* __restrict__ w2b1, const float* __restrict__ bias2,
        float* __restrict__ out, int n) {
    __shared__ __align__(16) short lt[16 * LROWS];
    int nbase = blockIdx.x * 16;
    int w = threadIdx.x >> 6;
    int wl = threadIdx.x & 63;
    int gl = wl & 15, q = wl >> 4;
    int gbase = wl & 48;
    unsigned lb = (unsigned)gl * 16u;
    int lrow = w * 4 + q;
    int node = nbase + lrow;
    const char* zb = (const char*)zin4;

    float a[8];
    #pragma unroll
    for (int t = 0; t < 8; t++) a[t] = 0.f;
    if (node < n) agg_node16(zb, rpse, esrc, node, n, gl, gbase, lb, a);
    short8 o;
    #pragma unroll
    for (int t = 0; t < 8; t++) o[t] = (short)f2b(a[t]);
    *(short8*)((char*)lt + lrow * (LROWS * 2) + lb) = o;
    __syncthreads();

    int m = gl;
    const short* ap = lt + m * LROWS + q * 8;
    short8 a0 = *(const short8*)(ap);
    short8 a1 = *(const short8*)(ap + 32);
    short8 a2 = *(const short8*)(ap + 64);
    short8 a3 = *(const short8*)(ap + 96);
    f32x4 acc[2];
    #pragma unroll
    for (int cc = 0; cc < 2; cc++) acc[cc] = (f32x4){0.f, 0.f, 0.f, 0.f};
    #pragma unroll
    for (int cc = 0; cc < 2; cc++) {
        int c = w * 2 + cc;
        const short* wp = (const short*)Wb + (c * 16 + m) * 128 + q * 8;
        short8 b0 = *(const short8*)(wp);
        short8 b1v = *(const short8*)(wp + 32);
        short8 b2v = *(const short8*)(wp + 64);
        short8 b3v = *(const short8*)(wp + 96);
        acc[cc] = __builtin_amdgcn_mfma_f32_16x16x32_bf16(a0, b0, acc[cc], 0, 0, 0);
        acc[cc] = __builtin_amdgcn_mfma_f32_16x16x32_bf16(a1, b1v, acc[cc], 0, 0, 0);
        acc[cc] = __builtin_amdgcn_mfma_f32_16x16x32_bf16(a2, b2v, acc[cc], 0, 0, 0);
        acc[cc] = __builtin_amdgcn_mfma_f32_16x16x32_bf16(a3, b3v, acc[cc], 0, 0, 0);
    }
    int row0 = nbase + q * 4;
    float degf[4];
    #pragma unroll
    for (int r = 0; r < 4; r++) {
        int nd = row0 + r;
        if (nd < n) {
            int2 se = rpse[nd];
            degf[r] = (float)(1 + se.y - se.x);
        } else degf[r] = 0.f;
    }
    #pragma unroll
    for (int cc = 0; cc < 2; cc++) {
        int col = (w * 2 + cc) * 16 + m;
        float wb = w2b1[col];
        float bb = bias2[col];
        #pragma unroll
        for (int r = 0; r < 4; r++) {
            int nd = row0 + r;
            if (nd < n) out[(size_t)nd * 128 + col] = acc[cc][r] + degf[r] * wb + bb;
        }
    }
}

// ---------------- launch ----------------

extern "C" void kernel_launch(void* const* d_in, const int* in_sizes, int n_in,
                              void* d_out, int out_size, void* d_ws, size_t ws_size,
                              hipStream_t stream) {
    const float* x  = (const float*)d_in[0];
    const int*   ei = (const int*)d_in[1];
    const float* W1 = (const float*)d_in[2];
    const float* b1 = (const float*)d_in[3];
    const float* W2 = (const float*)d_in[4];
    const float* b2 = (const float*)d_in[5];

    const int n = in_sizes[0] / DFEAT;   // 100000
    const int E = in_sizes[1] / 2;       // 1600000
    const int* src = ei;
    const int* dst = ei + E;
    const int nbuckets = (n + (1 << BSHIFT) - 1) >> BSHIFT;   // 391

    float* out = (float*)d_out;
    float* hid = out + (size_t)n * DFEAT;

    // xb lives in the dead `out` region (fp32 out = 51.2 MB >= 25.6 MB bf16
    // + zero row; out is only written by fused_agg_gemm2, after xb is dead).
    unsigned short* xb = (unsigned short*)out;

    // workspace: z1b(+zero row) | ebuf | esrc | rpse | bcur | weights
    char* w = (char*)d_ws;
    const size_t szB = (size_t)n * DFEAT * sizeof(unsigned short);   // 25.6 MB
    const size_t szB1 = szB + 4096;                                  // + zero row
    unsigned short* z1b = (unsigned short*)w;
    int* ebuf = (int*)(w + szB1);                 // nbuckets*CAP ints = 12.8 MB
    int* esrc = (int*)(w + szB1 + szB);           // nbuckets*CAP = 12.8 MB
    int2* rpse = (int2*)(esrc + (size_t)nbuckets * CAP);
    int* bcur = (int*)(rpse + n);
    char* wp = (char*)(bcur + NB_MAX);
    unsigned short* Wb1 = (unsigned short*)wp;
    unsigned short* Wcb = Wb1 + DFEAT * DFEAT;
    float* w2b1 = (float*)(Wcb + DFEAT * DFEAT);

    const int cast_blocks = (n * 32 + 255) / 256;   // 12500
    hipMemsetAsync(bcur, 0, nbuckets * sizeof(int), stream);
    scatter_cast<<<nbuckets + cast_blocks, 256, 0, stream>>>(
        src, dst, bcur, ebuf, E, nbuckets, x, xb, n * 32, n);
    csr_prep<<<nbuckets + 64, 256, 0, stream>>>(
        ebuf, bcur, rpse, esrc, n, nbuckets, W1, W2, b1, Wb1, Wcb, w2b1);

    const int fb = (n + 15) / 16;   // 6250
    fused_agg_gemm1<<<fb, 256, 0, stream>>>(
        (const ushort4*)xb, rpse, esrc, Wb1, b1, z1b, hid, n);
    fused_agg_gemm2<<<fb, 256, 0, stream>>>(
        (const ushort4*)z1b, rpse, esrc, Wcb, w2b1, b2, out, n);
}

// Round 5
// 358.424 us; speedup vs baseline: 1.1271x; 1.0386x over previous
//
#include <hip/hip_runtime.h>

// GIN 2-layer via linearity:
//   z1 = (I+A)x ; hid = z1@W1^T + b1
//   z2 = (I+A)z1 ; out = z2@(W2W1)^T + (1+deg)*(W2b1) + b2
// Round 5: R4 counters (occ 40%, hbm 31%, VGPR 56) => wave-internal
// serialization: only 8 gathers in flight, serial esrc->shfl chain per round.
// -> 16 gathers in flight (merged batches), indices for deg<=32 hoisted
//    before any gather issue. Rare deg>32 via 16-wide tail loop.

#define DFEAT 128
#define BSHIFT 8
#define NB_MAX 512
#define CAP 8192   // per-bucket capacity; mean 4096, 64-sigma safe
#define LROWS 136  // LDS row stride in shorts (272 B)

typedef __attribute__((ext_vector_type(8))) short short8;
typedef __attribute__((ext_vector_type(4))) float f32x4;

__device__ __forceinline__ float bf2f(unsigned short u) {
    union { unsigned int i; float f; } c;
    c.i = ((unsigned int)u) << 16;
    return c.f;
}
__device__ __forceinline__ unsigned short f2b(float f) {
    union { float f; unsigned int i; } c;
    c.f = f;
    unsigned int u = c.i;
    u = (u + 0x7FFFu + ((u >> 16) & 1u)) >> 16;   // RNE
    return (unsigned short)u;
}

// ---------------- fused bucket_scatter + cast_bf16 ----------------
// blocks [0,nscat): radix-bucket edge scatter. blocks [nscat,..): x -> bf16.
// bcur is a per-bucket COUNT (memset 0); absolute base = b*CAP + count.
// First cast block also zeroes xb row n (gather zero-row).

__global__ __launch_bounds__(256) void scatter_cast(const int* __restrict__ src,
                                                    const int* __restrict__ dst,
                                                    int* __restrict__ bcur,
                                                    int* __restrict__ ebuf, int E,
                                                    int nscat,
                                                    const float* __restrict__ x,
                                                    unsigned short* __restrict__ xb,
                                                    int total4, int nzero) {
    int tid = threadIdx.x;
    if (blockIdx.x >= nscat) {
        int i = (blockIdx.x - nscat) * 256 + tid;
        if (i < total4) {
            float4 v = ((const float4*)x)[i];
            ushort4 o;
            o.x = f2b(v.x); o.y = f2b(v.y); o.z = f2b(v.z); o.w = f2b(v.w);
            ((ushort4*)xb)[i] = o;
        }
        if (blockIdx.x == nscat && tid < 32)   // zero-row at index nzero
            ((ushort4*)xb)[(size_t)nzero * 32 + tid] = make_ushort4(0, 0, 0, 0);
        return;
    }
    __shared__ int lh[NB_MAX];
    for (int i = tid; i < NB_MAX; i += 256) lh[i] = 0;
    __syncthreads();
    int e0 = blockIdx.x * 4096;
    int e1 = min(e0 + 4096, E);
    int s[16], d[16];
    #pragma unroll
    for (int j = 0; j < 16; j++) {
        int e = e0 + tid + 256 * j;
        if (e < e1) { s[j] = src[e]; d[j] = dst[e]; atomicAdd(&lh[d[j] >> BSHIFT], 1); }
    }
    __syncthreads();
    for (int i = tid; i < NB_MAX; i += 256) {
        int c = lh[i];
        lh[i] = c ? (i * CAP + atomicAdd(&bcur[i], c)) : 0;  // absolute base
    }
    __syncthreads();
    #pragma unroll
    for (int j = 0; j < 16; j++) {
        int e = e0 + tid + 256 * j;
        if (e < e1) {
            int b = d[j] >> BSHIFT;
            int p = atomicAdd(&lh[b], 1);
            if (p < (b + 1) * CAP) ebuf[p] = (s[j] << 8) | (d[j] & 255);
        }
    }
}

// ---------------- fused build_csr + prep_w ----------------

__global__ __launch_bounds__(256) void csr_prep(const int* __restrict__ ebuf,
                                                const int* __restrict__ bcur,
                                                int2* __restrict__ rpse,
                                                int* __restrict__ esrc, int n, int nbk,
                                                const float* __restrict__ W1,
                                                const float* __restrict__ W2,
                                                const float* __restrict__ b1,
                                                unsigned short* __restrict__ Wb1,
                                                unsigned short* __restrict__ Wcb,
                                                float* __restrict__ w2b1) {
    int tid = threadIdx.x;
    if (blockIdx.x >= nbk) {
        // weight prep: rows i = (bb*2) and (bb*2+1)
        __shared__ float red[256];
        int bb = blockIdx.x - nbk;
        int i = bb * 2 + (tid >> 7);
        int j = tid & 127;
        float s = 0.f;
        #pragma unroll 4
        for (int k = 0; k < 128; k++) s += W2[i * 128 + k] * W1[k * 128 + j];
        Wcb[i * 128 + j] = f2b(s);
        Wb1[i * 128 + j] = f2b(W1[i * 128 + j]);
        red[tid] = W2[i * 128 + j] * b1[j];
        __syncthreads();
        if (j == 0) {
            float t = 0.f;
            for (int k = 0; k < 128; k++) t += red[tid + k];
            w2b1[i] = t;
        }
        return;
    }
    __shared__ int hist[256];
    __shared__ int wsum[4];
    __shared__ int woff2[4];
    int b = blockIdx.x;
    int nbase = b << BSHIFT;
    int e0 = b * CAP;
    int e1 = e0 + min(bcur[b], CAP);
    hist[tid] = 0;
    __syncthreads();
    for (int e = e0 + tid; e < e1; e += 256)
        atomicAdd(&hist[ebuf[e] & 255], 1);
    __syncthreads();
    int v = hist[tid];
    int lane = tid & 63, wid = tid >> 6;
    int inc = v;
    #pragma unroll
    for (int off = 1; off < 64; off <<= 1) {
        int u = __shfl_up(inc, off, 64);
        if (lane >= off) inc += u;
    }
    if (lane == 63) wsum[wid] = inc;
    __syncthreads();
    if (tid == 0) {
        int run = 0;
        #pragma unroll
        for (int w = 0; w < 4; w++) { woff2[w] = run; run += wsum[w]; }
    }
    __syncthreads();
    int excl = woff2[wid] + inc - v;
    int node = nbase + tid;
    if (node < n) rpse[node] = make_int2(e0 + excl, e0 + excl + v);
    __syncthreads();
    hist[tid] = excl;
    __syncthreads();
    for (int e = e0 + tid; e < e1; e += 256) {
        int le = ebuf[e];
        int p = atomicAdd(&hist[le & 255], 1);
        esrc[e0 + p] = ((unsigned int)le) >> 8;
    }
}

// ---------------- fused aggregation + GEMM (16 nodes/block) ----------------
// Phase A: one node per 16-lane group (4 nodes/wave). 16B/lane gathers,
// 16 in flight per round; rounds-1&2 indices hoisted (deg<=32 fast path);
// zero-row (index n) pads partial rounds -> branch-free issue.
// Phase B: 16-row MFMA tile from LDS; wave w computes col-blocks {2w, 2w+1}.

__device__ __forceinline__ void agg_node16(const char* __restrict__ zb,
                                           const int2* __restrict__ rpse,
                                           const int* __restrict__ esrc,
                                           int node, int nzero, int gl, int gbase,
                                           unsigned lb, float a[8]) {
    int2 se = rpse[node];
    int e0 = se.x, deg = se.y - se.x;
    short8 sv = *(const short8*)(zb + (unsigned)node * 256u + lb);
    #pragma unroll
    for (int t = 0; t < 8; t++) a[t] = bf2f((unsigned short)sv[t]);

    // hoisted indices for rounds 1 & 2 (deg <= 32 covers ~all nodes)
    int ei0 = (gl < deg) ? esrc[e0 + gl] : nzero;
    int ei1 = (gl + 16 < deg) ? esrc[e0 + gl + 16] : nzero;

    // round 1: 16 gathers in flight, then sum
    {
        unsigned off[16];
        short8 vv[16];
        #pragma unroll
        for (int k = 0; k < 16; k++)
            off[k] = (unsigned)__shfl(ei0, gbase + k) * 256u + lb;
        #pragma unroll
        for (int k = 0; k < 16; k++) vv[k] = *(const short8*)(zb + off[k]);
        #pragma unroll
        for (int k = 0; k < 16; k++) {
            #pragma unroll
            for (int t = 0; t < 8; t++) a[t] += bf2f((unsigned short)vv[k][t]);
        }
    }
    if (deg > 16) {
        unsigned off[16];
        short8 vv[16];
        #pragma unroll
        for (int k = 0; k < 16; k++)
            off[k] = (unsigned)__shfl(ei1, gbase + k) * 256u + lb;
        #pragma unroll
        for (int k = 0; k < 16; k++) vv[k] = *(const short8*)(zb + off[k]);
        #pragma unroll
        for (int k = 0; k < 16; k++) {
            #pragma unroll
            for (int t = 0; t < 8; t++) a[t] += bf2f((unsigned short)vv[k][t]);
        }
    }
    // rare deg > 32 tail: 16-wide rounds
    for (int rb = 32; rb < deg; rb += 16) {
        int eidx = (rb + gl < deg) ? esrc[e0 + rb + gl] : nzero;
        unsigned off[16];
        short8 vv[16];
        #pragma unroll
        for (int k = 0; k < 16; k++)
            off[k] = (unsigned)__shfl(eidx, gbase + k) * 256u + lb;
        #pragma unroll
        for (int k = 0; k < 16; k++) vv[k] = *(const short8*)(zb + off[k]);
        #pragma unroll
        for (int k = 0; k < 16; k++) {
            #pragma unroll
            for (int t = 0; t < 8; t++) a[t] += bf2f((unsigned short)vv[k][t]);
        }
    }
}

// layer 1: writes z1 (bf16, global, + zero row) + hid = z1@W1^T + b1
__global__ __launch_bounds__(256) void fused_agg_gemm1(
        const ushort4* __restrict__ zin4, const int2* __restrict__ rpse,
        const int* __restrict__ esrc, const unsigned short* __restrict__ Wb,
        const float* __restrict__ bias, unsigned short* __restrict__ zout,
        float* __restrict__ out, int n) {
    __shared__ __align__(16) short lt[16 * LROWS];
    int nbase = blockIdx.x * 16;
    int w = threadIdx.x >> 6;
    int wl = threadIdx.x & 63;
    int gl = wl & 15, q = wl >> 4;
    int gbase = wl & 48;
    unsigned lb = (unsigned)gl * 16u;
    int lrow = w * 4 + q;
    int node = nbase + lrow;
    const char* zb = (const char*)zin4;

    float a[8];
    #pragma unroll
    for (int t = 0; t < 8; t++) a[t] = 0.f;
    if (node < n) agg_node16(zb, rpse, esrc, node, n, gl, gbase, lb, a);
    short8 o;
    #pragma unroll
    for (int t = 0; t < 8; t++) o[t] = (short)f2b(a[t]);
    *(short8*)((char*)lt + lrow * (LROWS * 2) + lb) = o;
    if (node < n) *(short8*)((char*)zout + (unsigned)node * 256u + lb) = o;
    if (blockIdx.x == 0 && threadIdx.x < 16) {   // zero-row for layer-2 gathers
        short8 z8;
        #pragma unroll
        for (int t = 0; t < 8; t++) z8[t] = 0;
        *(short8*)((char*)zout + (unsigned)n * 256u + threadIdx.x * 16) = z8;
    }
    __syncthreads();

    int m = gl;
    const short* ap = lt + m * LROWS + q * 8;
    short8 a0 = *(const short8*)(ap);
    short8 a1 = *(const short8*)(ap + 32);
    short8 a2 = *(const short8*)(ap + 64);
    short8 a3 = *(const short8*)(ap + 96);
    f32x4 acc[2];
    #pragma unroll
    for (int cc = 0; cc < 2; cc++) acc[cc] = (f32x4){0.f, 0.f, 0.f, 0.f};
    #pragma unroll
    for (int cc = 0; cc < 2; cc++) {
        int c = w * 2 + cc;
        const short* wp = (const short*)Wb + (c * 16 + m) * 128 + q * 8;
        short8 b0 = *(const short8*)(wp);
        short8 b1v = *(const short8*)(wp + 32);
        short8 b2v = *(const short8*)(wp + 64);
        short8 b3v = *(const short8*)(wp + 96);
        acc[cc] = __builtin_amdgcn_mfma_f32_16x16x32_bf16(a0, b0, acc[cc], 0, 0, 0);
        acc[cc] = __builtin_amdgcn_mfma_f32_16x16x32_bf16(a1, b1v, acc[cc], 0, 0, 0);
        acc[cc] = __builtin_amdgcn_mfma_f32_16x16x32_bf16(a2, b2v, acc[cc], 0, 0, 0);
        acc[cc] = __builtin_amdgcn_mfma_f32_16x16x32_bf16(a3, b3v, acc[cc], 0, 0, 0);
    }
    int row0 = nbase + q * 4;
    #pragma unroll
    for (int cc = 0; cc < 2; cc++) {
        int col = (w * 2 + cc) * 16 + m;
        float bb = bias[col];
        #pragma unroll
        for (int r = 0; r < 4; r++) {
            int nd = row0 + r;
            if (nd < n) out[(size_t)nd * 128 + col] = acc[cc][r] + bb;
        }
    }
}

// layer 2: z2 never materialized; out = z2@Wc^T + (1+deg)*w2b1 + b2
__global__ __launch_bounds__(256) void fused_agg_gemm2(
        const ushort4* __restrict__ zin4, const int2* __restrict__ rpse,
        const int* __restrict__ esrc, const unsigned short* __restrict__ Wb,
        const float* __restrict__ w2b1, const float* __restrict__ bias2,
        float* __restrict__ out, int n) {
    __shared__ __align__(16) short lt[16 * LROWS];
    int nbase = blockIdx.x * 16;
    int w = threadIdx.x >> 6;
    int wl = threadIdx.x & 63;
    int gl = wl & 15, q = wl >> 4;
    int gbase = wl & 48;
    unsigned lb = (unsigned)gl * 16u;
    int lrow = w * 4 + q;
    int node = nbase + lrow;
    const char* zb = (const char*)zin4;

    float a[8];
    #pragma unroll
    for (int t = 0; t < 8; t++) a[t] = 0.f;
    if (node < n) agg_node16(zb, rpse, esrc, node, n, gl, gbase, lb, a);
    short8 o;
    #pragma unroll
    for (int t = 0; t < 8; t++) o[t] = (short)f2b(a[t]);
    *(short8*)((char*)lt + lrow * (LROWS * 2) + lb) = o;
    __syncthreads();

    int m = gl;
    const short* ap = lt + m * LROWS + q * 8;
    short8 a0 = *(const short8*)(ap);
    short8 a1 = *(const short8*)(ap + 32);
    short8 a2 = *(const short8*)(ap + 64);
    short8 a3 = *(const short8*)(ap + 96);
    f32x4 acc[2];
    #pragma unroll
    for (int cc = 0; cc < 2; cc++) acc[cc] = (f32x4){0.f, 0.f, 0.f, 0.f};
    #pragma unroll
    for (int cc = 0; cc < 2; cc++) {
        int c = w * 2 + cc;
        const short* wp = (const short*)Wb + (c * 16 + m) * 128 + q * 8;
        short8 b0 = *(const short8*)(wp);
        short8 b1v = *(const short8*)(wp + 32);
        short8 b2v = *(const short8*)(wp + 64);
        short8 b3v = *(const short8*)(wp + 96);
        acc[cc] = __builtin_amdgcn_mfma_f32_16x16x32_bf16(a0, b0, acc[cc], 0, 0, 0);
        acc[cc] = __builtin_amdgcn_mfma_f32_16x16x32_bf16(a1, b1v, acc[cc], 0, 0, 0);
        acc[cc] = __builtin_amdgcn_mfma_f32_16x16x32_bf16(a2, b2v, acc[cc], 0, 0, 0);
        acc[cc] = __builtin_amdgcn_mfma_f32_16x16x32_bf16(a3, b3v, acc[cc], 0, 0, 0);
    }
    int row0 = nbase + q * 4;
    float degf[4];
    #pragma unroll
    for (int r = 0; r < 4; r++) {
        int nd = row0 + r;
        if (nd < n) {
            int2 se = rpse[nd];
            degf[r] = (float)(1 + se.y - se.x);
        } else degf[r] = 0.f;
    }
    #pragma unroll
    for (int cc = 0; cc < 2; cc++) {
        int col = (w * 2 + cc) * 16 + m;
        float wb = w2b1[col];
        float bb = bias2[col];
        #pragma unroll
        for (int r = 0; r < 4; r++) {
            int nd = row0 + r;
            if (nd < n) out[(size_t)nd * 128 + col] = acc[cc][r] + degf[r] * wb + bb;
        }
    }
}

// ---------------- launch ----------------

extern "C" void kernel_launch(void* const* d_in, const int* in_sizes, int n_in,
                              void* d_out, int out_size, void* d_ws, size_t ws_size,
                              hipStream_t stream) {
    const float* x  = (const float*)d_in[0];
    const int*   ei = (const int*)d_in[1];
    const float* W1 = (const float*)d_in[2];
    const float* b1 = (const float*)d_in[3];
    const float* W2 = (const float*)d_in[4];
    const float* b2 = (const float*)d_in[5];

    const int n = in_sizes[0] / DFEAT;   // 100000
    const int E = in_sizes[1] / 2;       // 1600000
    const int* src = ei;
    const int* dst = ei + E;
    const int nbuckets = (n + (1 << BSHIFT) - 1) >> BSHIFT;   // 391

    float* out = (float*)d_out;
    float* hid = out + (size_t)n * DFEAT;

    // xb lives in the dead `out` region (fp32 out = 51.2 MB >= 25.6 MB bf16
    // + zero row; out is only written by fused_agg_gemm2, after xb is dead).
    unsigned short* xb = (unsigned short*)out;

    // workspace: z1b(+zero row) | ebuf | esrc | rpse | bcur | weights
    char* w = (char*)d_ws;
    const size_t szB = (size_t)n * DFEAT * sizeof(unsigned short);   // 25.6 MB
    const size_t szB1 = szB + 4096;                                  // + zero row
    unsigned short* z1b = (unsigned short*)w;
    int* ebuf = (int*)(w + szB1);                 // nbuckets*CAP ints = 12.8 MB
    int* esrc = (int*)(w + szB1 + szB);           // nbuckets*CAP = 12.8 MB
    int2* rpse = (int2*)(esrc + (size_t)nbuckets * CAP);
    int* bcur = (int*)(rpse + n);
    char* wp = (char*)(bcur + NB_MAX);
    unsigned short* Wb1 = (unsigned short*)wp;
    unsigned short* Wcb = Wb1 + DFEAT * DFEAT;
    float* w2b1 = (float*)(Wcb + DFEAT * DFEAT);

    const int cast_blocks = (n * 32 + 255) / 256;   // 12500
    hipMemsetAsync(bcur, 0, nbuckets * sizeof(int), stream);
    scatter_cast<<<nbuckets + cast_blocks, 256, 0, stream>>>(
        src, dst, bcur, ebuf, E, nbuckets, x, xb, n * 32, n);
    csr_prep<<<nbuckets + 64, 256, 0, stream>>>(
        ebuf, bcur, rpse, esrc, n, nbuckets, W1, W2, b1, Wb1, Wcb, w2b1);

    const int fb = (n + 15) / 16;   // 6250
    fused_agg_gemm1<<<fb, 256, 0, stream>>>(
        (const ushort4*)xb, rpse, esrc, Wb1, b1, z1b, hid, n);
    fused_agg_gemm2<<<fb, 256, 0, stream>>>(
        (const ushort4*)z1b, rpse, esrc, Wcb, w2b1, b2, out, n);
}

// Round 7
// 326.192 us; speedup vs baseline: 1.2385x; 1.0988x over previous
//
#include <hip/hip_runtime.h>

// GIN 2-layer via linearity:
//   z1 = (I+A)x ; hid = z1@W1^T + b1
//   z2 = (I+A)z1 ; out = z2@(W2W1)^T + (1+deg)*(W2b1) + b2
// Round 6 (resubmit; R6 bench was an infra failure): R5 counters (occ 29%,
// hbm 36%, mfma 1.3%) => exposed per-wave dependency chain
// rpse->esrc->gather, paid once per tile.
// -> persistent blocks (2048) looping over 16-node tiles; next tile's
//    rpse/esrc prefetch issued while current tile's 16 gathers are in
//    flight. Prologue chain amortized over ~3 tiles/block.

#define DFEAT 128
#define BSHIFT 8
#define NB_MAX 512
#define CAP 8192   // per-bucket capacity; mean 4096, 64-sigma safe
#define LROWS 136  // LDS row stride in shorts (272 B)
#define AGG_BLOCKS 2048

typedef __attribute__((ext_vector_type(8))) short short8;
typedef __attribute__((ext_vector_type(4))) float f32x4;

__device__ __forceinline__ float bf2f(unsigned short u) {
    union { unsigned int i; float f; } c;
    c.i = ((unsigned int)u) << 16;
    return c.f;
}
__device__ __forceinline__ unsigned short f2b(float f) {
    union { float f; unsigned int i; } c;
    c.f = f;
    unsigned int u = c.i;
    u = (u + 0x7FFFu + ((u >> 16) & 1u)) >> 16;   // RNE
    return (unsigned short)u;
}

// ---------------- fused bucket_scatter + cast_bf16 ----------------

__global__ __launch_bounds__(256) void scatter_cast(const int* __restrict__ src,
                                                    const int* __restrict__ dst,
                                                    int* __restrict__ bcur,
                                                    int* __restrict__ ebuf, int E,
                                                    int nscat,
                                                    const float* __restrict__ x,
                                                    unsigned short* __restrict__ xb,
                                                    int total4, int nzero) {
    int tid = threadIdx.x;
    if (blockIdx.x >= nscat) {
        int i = (blockIdx.x - nscat) * 256 + tid;
        if (i < total4) {
            float4 v = ((const float4*)x)[i];
            ushort4 o;
            o.x = f2b(v.x); o.y = f2b(v.y); o.z = f2b(v.z); o.w = f2b(v.w);
            ((ushort4*)xb)[i] = o;
        }
        if (blockIdx.x == nscat && tid < 32)   // zero-row at index nzero
            ((ushort4*)xb)[(size_t)nzero * 32 + tid] = make_ushort4(0, 0, 0, 0);
        return;
    }
    __shared__ int lh[NB_MAX];
    for (int i = tid; i < NB_MAX; i += 256) lh[i] = 0;
    __syncthreads();
    int e0 = blockIdx.x * 4096;
    int e1 = min(e0 + 4096, E);
    int s[16], d[16];
    #pragma unroll
    for (int j = 0; j < 16; j++) {
        int e = e0 + tid + 256 * j;
        if (e < e1) { s[j] = src[e]; d[j] = dst[e]; atomicAdd(&lh[d[j] >> BSHIFT], 1); }
    }
    __syncthreads();
    for (int i = tid; i < NB_MAX; i += 256) {
        int c = lh[i];
        lh[i] = c ? (i * CAP + atomicAdd(&bcur[i], c)) : 0;  // absolute base
    }
    __syncthreads();
    #pragma unroll
    for (int j = 0; j < 16; j++) {
        int e = e0 + tid + 256 * j;
        if (e < e1) {
            int b = d[j] >> BSHIFT;
            int p = atomicAdd(&lh[b], 1);
            if (p < (b + 1) * CAP) ebuf[p] = (s[j] << 8) | (d[j] & 255);
        }
    }
}

// ---------------- fused build_csr + prep_w ----------------

__global__ __launch_bounds__(256) void csr_prep(const int* __restrict__ ebuf,
                                                const int* __restrict__ bcur,
                                                int2* __restrict__ rpse,
                                                int* __restrict__ esrc, int n, int nbk,
                                                const float* __restrict__ W1,
                                                const float* __restrict__ W2,
                                                const float* __restrict__ b1,
                                                unsigned short* __restrict__ Wb1,
                                                unsigned short* __restrict__ Wcb,
                                                float* __restrict__ w2b1) {
    int tid = threadIdx.x;
    if (blockIdx.x >= nbk) {
        __shared__ float red[256];
        int bb = blockIdx.x - nbk;
        int i = bb * 2 + (tid >> 7);
        int j = tid & 127;
        float s = 0.f;
        #pragma unroll 4
        for (int k = 0; k < 128; k++) s += W2[i * 128 + k] * W1[k * 128 + j];
        Wcb[i * 128 + j] = f2b(s);
        Wb1[i * 128 + j] = f2b(W1[i * 128 + j]);
        red[tid] = W2[i * 128 + j] * b1[j];
        __syncthreads();
        if (j == 0) {
            float t = 0.f;
            for (int k = 0; k < 128; k++) t += red[tid + k];
            w2b1[i] = t;
        }
        return;
    }
    __shared__ int hist[256];
    __shared__ int wsum[4];
    __shared__ int woff2[4];
    int b = blockIdx.x;
    int nbase = b << BSHIFT;
    int e0 = b * CAP;
    int e1 = e0 + min(bcur[b], CAP);
    hist[tid] = 0;
    __syncthreads();
    for (int e = e0 + tid; e < e1; e += 256)
        atomicAdd(&hist[ebuf[e] & 255], 1);
    __syncthreads();
    int v = hist[tid];
    int lane = tid & 63, wid = tid >> 6;
    int inc = v;
    #pragma unroll
    for (int off = 1; off < 64; off <<= 1) {
        int u = __shfl_up(inc, off, 64);
        if (lane >= off) inc += u;
    }
    if (lane == 63) wsum[wid] = inc;
    __syncthreads();
    if (tid == 0) {
        int run = 0;
        #pragma unroll
        for (int w = 0; w < 4; w++) { woff2[w] = run; run += wsum[w]; }
    }
    __syncthreads();
    int excl = woff2[wid] + inc - v;
    int node = nbase + tid;
    if (node < n) rpse[node] = make_int2(e0 + excl, e0 + excl + v);
    __syncthreads();
    hist[tid] = excl;
    __syncthreads();
    for (int e = e0 + tid; e < e1; e += 256) {
        int le = ebuf[e];
        int p = atomicAdd(&hist[le & 255], 1);
        esrc[e0 + p] = ((unsigned int)le) >> 8;
    }
}

// ---------------- fused aggregation + GEMM (persistent, pipelined) ----------
// One node per 16-lane group; tiles of 16 nodes; grid-stride tile loop with
// next-tile rpse/esrc prefetch overlapped with current tile's 16 in-flight
// gathers. Zero-row (index n) pads everything -> branch-free issue.

// layer 1: writes z1 (bf16, global, + zero row) + hid = z1@W1^T + b1
__global__ __launch_bounds__(256) void fused_agg_gemm1(
        const ushort4* __restrict__ zin4, const int2* __restrict__ rpse,
        const int* __restrict__ esrc, const unsigned short* __restrict__ Wb,
        const float* __restrict__ bias, unsigned short* __restrict__ zout,
        float* __restrict__ out, int n, int ntiles) {
    __shared__ __align__(16) short lt[16 * LROWS];
    int w = threadIdx.x >> 6;
    int wl = threadIdx.x & 63;
    int gl = wl & 15, q = wl >> 4;
    int gbase = wl & 48;
    unsigned lb = (unsigned)gl * 16u;
    int lrow = w * 4 + q;
    const char* zb = (const char*)zin4;
    const int stride = gridDim.x;

    if (blockIdx.x == 0 && threadIdx.x < 16) {   // zero-row for layer-2 gathers
        short8 z8;
        #pragma unroll
        for (int t = 0; t < 8; t++) z8[t] = 0;
        *(short8*)((char*)zout + (unsigned)n * 256u + threadIdx.x * 16) = z8;
    }

    float bb[2];
    #pragma unroll
    for (int cc = 0; cc < 2; cc++) bb[cc] = bias[(w * 2 + cc) * 16 + gl];

    // prologue prefetch for first tile
    int t = blockIdx.x;
    int node = t * 16 + lrow;
    int2 se = make_int2(0, 0);
    if (t < ntiles && node < n) se = rpse[node];
    int deg0 = se.y - se.x;
    int ei0 = (t < ntiles && node < n && gl < deg0) ? esrc[se.x + gl] : n;
    int ei1 = (t < ntiles && node < n && gl + 16 < deg0) ? esrc[se.x + gl + 16] : n;

    for (; t < ntiles; ) {
        int tn = t + stride;
        int node_n = tn * 16 + lrow;
        int2 se_n = make_int2(0, 0);
        if (tn < ntiles && node_n < n) se_n = rpse[node_n];   // issue early

        // self row (clamp to zero-row for OOB)
        int node_c = node < n ? node : n;
        float a[8];
        short8 sv = *(const short8*)(zb + (unsigned)node_c * 256u + lb);
        #pragma unroll
        for (int tt = 0; tt < 8; tt++) a[tt] = bf2f((unsigned short)sv[tt]);

        // round 1: 16 gathers in flight
        unsigned off[16];
        short8 vv[16];
        #pragma unroll
        for (int k = 0; k < 16; k++)
            off[k] = (unsigned)__shfl(ei0, gbase + k) * 256u + lb;
        #pragma unroll
        for (int k = 0; k < 16; k++) vv[k] = *(const short8*)(zb + off[k]);

        // prefetch next tile's indices (se_n wait overlaps in-flight gathers)
        int deg_n = se_n.y - se_n.x;
        int ei0_n = n, ei1_n = n;
        if (tn < ntiles && node_n < n) {
            if (gl < deg_n)      ei0_n = esrc[se_n.x + gl];
            if (gl + 16 < deg_n) ei1_n = esrc[se_n.x + gl + 16];
        }

        #pragma unroll
        for (int k = 0; k < 16; k++) {
            #pragma unroll
            for (int tt = 0; tt < 8; tt++) a[tt] += bf2f((unsigned short)vv[k][tt]);
        }
        int deg = se.y - se.x;
        if (deg > 16) {
            unsigned o2[16];
            short8 v2[16];
            #pragma unroll
            for (int k = 0; k < 16; k++)
                o2[k] = (unsigned)__shfl(ei1, gbase + k) * 256u + lb;
            #pragma unroll
            for (int k = 0; k < 16; k++) v2[k] = *(const short8*)(zb + o2[k]);
            #pragma unroll
            for (int k = 0; k < 16; k++) {
                #pragma unroll
                for (int tt = 0; tt < 8; tt++) a[tt] += bf2f((unsigned short)v2[k][tt]);
            }
        }
        for (int rb = 32; rb < deg; rb += 16) {   // rare deg > 32 tail
            int eidx = (rb + gl < deg) ? esrc[se.x + rb + gl] : n;
            unsigned o2[16];
            short8 v2[16];
            #pragma unroll
            for (int k = 0; k < 16; k++)
                o2[k] = (unsigned)__shfl(eidx, gbase + k) * 256u + lb;
            #pragma unroll
            for (int k = 0; k < 16; k++) v2[k] = *(const short8*)(zb + o2[k]);
            #pragma unroll
            for (int k = 0; k < 16; k++) {
                #pragma unroll
                for (int tt = 0; tt < 8; tt++) a[tt] += bf2f((unsigned short)v2[k][tt]);
            }
        }

        short8 o;
        #pragma unroll
        for (int tt = 0; tt < 8; tt++) o[tt] = (short)f2b(a[tt]);
        *(short8*)((char*)lt + lrow * (LROWS * 2) + lb) = o;
        if (node < n) *(short8*)((char*)zout + (unsigned)node * 256u + lb) = o;
        __syncthreads();

        // GEMM: 16-row tile, wave w does col-blocks {2w, 2w+1}
        int m = gl;
        const short* ap = lt + m * LROWS + q * 8;
        short8 a0 = *(const short8*)(ap);
        short8 a1 = *(const short8*)(ap + 32);
        short8 a2 = *(const short8*)(ap + 64);
        short8 a3 = *(const short8*)(ap + 96);
        f32x4 acc[2];
        #pragma unroll
        for (int cc = 0; cc < 2; cc++) acc[cc] = (f32x4){0.f, 0.f, 0.f, 0.f};
        #pragma unroll
        for (int cc = 0; cc < 2; cc++) {
            int c = w * 2 + cc;
            const short* wp = (const short*)Wb + (c * 16 + m) * 128 + q * 8;
            short8 b0 = *(const short8*)(wp);
            short8 b1v = *(const short8*)(wp + 32);
            short8 b2v = *(const short8*)(wp + 64);
            short8 b3v = *(const short8*)(wp + 96);
            acc[cc] = __builtin_amdgcn_mfma_f32_16x16x32_bf16(a0, b0, acc[cc], 0, 0, 0);
            acc[cc] = __builtin_amdgcn_mfma_f32_16x16x32_bf16(a1, b1v, acc[cc], 0, 0, 0);
            acc[cc] = __builtin_amdgcn_mfma_f32_16x16x32_bf16(a2, b2v, acc[cc], 0, 0, 0);
            acc[cc] = __builtin_amdgcn_mfma_f32_16x16x32_bf16(a3, b3v, acc[cc], 0, 0, 0);
        }
        int row0 = t * 16 + q * 4;
        #pragma unroll
        for (int cc = 0; cc < 2; cc++) {
            int col = (w * 2 + cc) * 16 + m;
            #pragma unroll
            for (int r = 0; r < 4; r++) {
                int nd = row0 + r;
                if (nd < n) out[(size_t)nd * 128 + col] = acc[cc][r] + bb[cc];
            }
        }
        __syncthreads();

        se = se_n; ei0 = ei0_n; ei1 = ei1_n; node = node_n; t = tn;
    }
}

// layer 2: z2 never materialized; out = z2@Wc^T + (1+deg)*w2b1 + b2
__global__ __launch_bounds__(256) void fused_agg_gemm2(
        const ushort4* __restrict__ zin4, const int2* __restrict__ rpse,
        const int* __restrict__ esrc, const unsigned short* __restrict__ Wb,
        const float* __restrict__ w2b1, const float* __restrict__ bias2,
        float* __restrict__ out, int n, int ntiles) {
    __shared__ __align__(16) short lt[16 * LROWS];
    int w = threadIdx.x >> 6;
    int wl = threadIdx.x & 63;
    int gl = wl & 15, q = wl >> 4;
    int gbase = wl & 48;
    unsigned lb = (unsigned)gl * 16u;
    int lrow = w * 4 + q;
    const char* zb = (const char*)zin4;
    const int stride = gridDim.x;

    float wb2[2], bb2[2];
    #pragma unroll
    for (int cc = 0; cc < 2; cc++) {
        int col = (w * 2 + cc) * 16 + gl;
        wb2[cc] = w2b1[col];
        bb2[cc] = bias2[col];
    }

    int t = blockIdx.x;
    int node = t * 16 + lrow;
    int2 se = make_int2(0, 0);
    if (t < ntiles && node < n) se = rpse[node];
    int deg0 = se.y - se.x;
    int ei0 = (t < ntiles && node < n && gl < deg0) ? esrc[se.x + gl] : n;
    int ei1 = (t < ntiles && node < n && gl + 16 < deg0) ? esrc[se.x + gl + 16] : n;

    for (; t < ntiles; ) {
        int tn = t + stride;
        int node_n = tn * 16 + lrow;
        int2 se_n = make_int2(0, 0);
        if (tn < ntiles && node_n < n) se_n = rpse[node_n];   // issue early

        int node_c = node < n ? node : n;
        float a[8];
        short8 sv = *(const short8*)(zb + (unsigned)node_c * 256u + lb);
        #pragma unroll
        for (int tt = 0; tt < 8; tt++) a[tt] = bf2f((unsigned short)sv[tt]);

        unsigned off[16];
        short8 vv[16];
        #pragma unroll
        for (int k = 0; k < 16; k++)
            off[k] = (unsigned)__shfl(ei0, gbase + k) * 256u + lb;
        #pragma unroll
        for (int k = 0; k < 16; k++) vv[k] = *(const short8*)(zb + off[k]);

        int deg_n = se_n.y - se_n.x;
        int ei0_n = n, ei1_n = n;
        if (tn < ntiles && node_n < n) {
            if (gl < deg_n)      ei0_n = esrc[se_n.x + gl];
            if (gl + 16 < deg_n) ei1_n = esrc[se_n.x + gl + 16];
        }

        #pragma unroll
        for (int k = 0; k < 16; k++) {
            #pragma unroll
            for (int tt = 0; tt < 8; tt++) a[tt] += bf2f((unsigned short)vv[k][tt]);
        }
        int deg = se.y - se.x;
        if (deg > 16) {
            unsigned o2[16];
            short8 v2[16];
            #pragma unroll
            for (int k = 0; k < 16; k++)
                o2[k] = (unsigned)__shfl(ei1, gbase + k) * 256u + lb;
            #pragma unroll
            for (int k = 0; k < 16; k++) v2[k] = *(const short8*)(zb + o2[k]);
            #pragma unroll
            for (int k = 0; k < 16; k++) {
                #pragma unroll
                for (int tt = 0; tt < 8; tt++) a[tt] += bf2f((unsigned short)v2[k][tt]);
            }
        }
        for (int rb = 32; rb < deg; rb += 16) {
            int eidx = (rb + gl < deg) ? esrc[se.x + rb + gl] : n;
            unsigned o2[16];
            short8 v2[16];
            #pragma unroll
            for (int k = 0; k < 16; k++)
                o2[k] = (unsigned)__shfl(eidx, gbase + k) * 256u + lb;
            #pragma unroll
            for (int k = 0; k < 16; k++) v2[k] = *(const short8*)(zb + o2[k]);
            #pragma unroll
            for (int k = 0; k < 16; k++) {
                #pragma unroll
                for (int tt = 0; tt < 8; tt++) a[tt] += bf2f((unsigned short)v2[k][tt]);
            }
        }

        short8 o;
        #pragma unroll
        for (int tt = 0; tt < 8; tt++) o[tt] = (short)f2b(a[tt]);
        *(short8*)((char*)lt + lrow * (LROWS * 2) + lb) = o;
        __syncthreads();

        int m = gl;
        const short* ap = lt + m * LROWS + q * 8;
        short8 a0 = *(const short8*)(ap);
        short8 a1 = *(const short8*)(ap + 32);
        short8 a2 = *(const short8*)(ap + 64);
        short8 a3 = *(const short8*)(ap + 96);
        f32x4 acc[2];
        #pragma unroll
        for (int cc = 0; cc < 2; cc++) acc[cc] = (f32x4){0.f, 0.f, 0.f, 0.f};
        #pragma unroll
        for (int cc = 0; cc < 2; cc++) {
            int c = w * 2 + cc;
            const short* wp = (const short*)Wb + (c * 16 + m) * 128 + q * 8;
            short8 b0 = *(const short8*)(wp);
            short8 b1v = *(const short8*)(wp + 32);
            short8 b2v = *(const short8*)(wp + 64);
            short8 b3v = *(const short8*)(wp + 96);
            acc[cc] = __builtin_amdgcn_mfma_f32_16x16x32_bf16(a0, b0, acc[cc], 0, 0, 0);
            acc[cc] = __builtin_amdgcn_mfma_f32_16x16x32_bf16(a1, b1v, acc[cc], 0, 0, 0);
            acc[cc] = __builtin_amdgcn_mfma_f32_16x16x32_bf16(a2, b2v, acc[cc], 0, 0, 0);
            acc[cc] = __builtin_amdgcn_mfma_f32_16x16x32_bf16(a3, b3v, acc[cc], 0, 0, 0);
        }
        int row0 = t * 16 + q * 4;
        float degf[4];
        #pragma unroll
        for (int r = 0; r < 4; r++) {
            int nd = row0 + r;
            if (nd < n) {
                int2 s2 = rpse[nd];
                degf[r] = (float)(1 + s2.y - s2.x);
            } else degf[r] = 0.f;
        }
        #pragma unroll
        for (int cc = 0; cc < 2; cc++) {
            int col = (w * 2 + cc) * 16 + m;
            #pragma unroll
            for (int r = 0; r < 4; r++) {
                int nd = row0 + r;
                if (nd < n) out[(size_t)nd * 128 + col] = acc[cc][r] + degf[r] * wb2[cc] + bb2[cc];
            }
        }
        __syncthreads();

        se = se_n; ei0 = ei0_n; ei1 = ei1_n; node = node_n; t = tn;
    }
}

// ---------------- launch ----------------

extern "C" void kernel_launch(void* const* d_in, const int* in_sizes, int n_in,
                              void* d_out, int out_size, void* d_ws, size_t ws_size,
                              hipStream_t stream) {
    const float* x  = (const float*)d_in[0];
    const int*   ei = (const int*)d_in[1];
    const float* W1 = (const float*)d_in[2];
    const float* b1 = (const float*)d_in[3];
    const float* W2 = (const float*)d_in[4];
    const float* b2 = (const float*)d_in[5];

    const int n = in_sizes[0] / DFEAT;   // 100000
    const int E = in_sizes[1] / 2;       // 1600000
    const int* src = ei;
    const int* dst = ei + E;
    const int nbuckets = (n + (1 << BSHIFT) - 1) >> BSHIFT;   // 391

    float* out = (float*)d_out;
    float* hid = out + (size_t)n * DFEAT;

    // xb lives in the dead `out` region (fp32 out = 51.2 MB >= 25.6 MB bf16
    // + zero row; out is only written by fused_agg_gemm2, after xb is dead).
    unsigned short* xb = (unsigned short*)out;

    // workspace: z1b(+zero row) | ebuf | esrc | rpse | bcur | weights
    char* w = (char*)d_ws;
    const size_t szB = (size_t)n * DFEAT * sizeof(unsigned short);   // 25.6 MB
    const size_t szB1 = szB + 4096;                                  // + zero row
    unsigned short* z1b = (unsigned short*)w;
    int* ebuf = (int*)(w + szB1);                 // nbuckets*CAP ints = 12.8 MB
    int* esrc = (int*)(w + szB1 + szB);           // nbuckets*CAP = 12.8 MB
    int2* rpse = (int2*)(esrc + (size_t)nbuckets * CAP);
    int* bcur = (int*)(rpse + n);
    char* wp = (char*)(bcur + NB_MAX);
    unsigned short* Wb1 = (unsigned short*)wp;
    unsigned short* Wcb = Wb1 + DFEAT * DFEAT;
    float* w2b1 = (float*)(Wcb + DFEAT * DFEAT);

    const int cast_blocks = (n * 32 + 255) / 256;   // 12500
    hipMemsetAsync(bcur, 0, nbuckets * sizeof(int), stream);
    scatter_cast<<<nbuckets + cast_blocks, 256, 0, stream>>>(
        src, dst, bcur, ebuf, E, nbuckets, x, xb, n * 32, n);
    csr_prep<<<nbuckets + 64, 256, 0, stream>>>(
        ebuf, bcur, rpse, esrc, n, nbuckets, W1, W2, b1, Wb1, Wcb, w2b1);

    const int ntiles = (n + 15) / 16;   // 6250
    const int fb = AGG_BLOCKS;          // persistent, grid-stride tiles
    fused_agg_gemm1<<<fb, 256, 0, stream>>>(
        (const ushort4*)xb, rpse, esrc, Wb1, b1, z1b, hid, n, ntiles);
    fused_agg_gemm2<<<fb, 256, 0, stream>>>(
        (const ushort4*)z1b, rpse, esrc, Wcb, w2b1, b2, out, n, ntiles);
}